// Round 1
// baseline (171.748 us; speedup 1.0000x reference)
//
#include <hip/hip_runtime.h>

// RT-DETR Hungarian matcher cost matrix.
// B=32, Q=300, C=80, T=100. Out: (B*Q) x (B*T) = 9600 x 3200 fp32.
// cost = 5*L1(center boxes) + 2*focal_class_cost + 2*(-GIoU)
//
// class_cost depends only on (query, label[j]) -> precompute 9600x80 table
// (removes exp/log from the 30.7M-element pair loop).

constexpr int BB = 32, QQ = 300, CN = 80, TT = 100;
constexpr int NQ = BB * QQ;   // 9600 queries
constexpr int NT = BB * TT;   // 3200 targets
constexpr int JQ = NT / 4;    // 800 float4 groups per row

__global__ __launch_bounds__(256) void class_cost_kernel(
    const float* __restrict__ logits, float* __restrict__ cc2, int n) {
  int idx = blockIdx.x * blockDim.x + threadIdx.x;
  if (idx >= n) return;
  float x = logits[idx];
  float p = 1.0f / (1.0f + expf(-x));
  float neg = 0.75f * p * p * (-logf(1.0f - p + 1e-8f));
  float pos = 0.25f * (1.0f - p) * (1.0f - p) * (-logf(p + 1e-8f));
  cc2[idx] = 2.0f * (pos - neg);   // pre-scaled by C_CLASS=2
}

template <bool USE_TABLE>
__global__ __launch_bounds__(256) void pair_kernel(
    const float4* __restrict__ pred_boxes,    // NQ   (cx,cy,w,h)
    const float4* __restrict__ target_boxes,  // NT   (cx,cy,w,h)
    const int4*   __restrict__ labels4,       // NT/4
    const float*  __restrict__ cc2,           // NQ*80 (if USE_TABLE)
    const float*  __restrict__ logits,        // NQ*80 (fallback)
    float4*       __restrict__ out)           // NQ * NT/4
{
  int tid = blockIdx.x * blockDim.x + threadIdx.x;
  if (tid >= NQ * JQ) return;
  int i  = tid / JQ;          // query row
  int jq = tid - i * JQ;      // target group

  float4 p = pred_boxes[i];
  float px0 = p.x - 0.5f * p.z, py0 = p.y - 0.5f * p.w;
  float px1 = p.x + 0.5f * p.z, py1 = p.y + 0.5f * p.w;
  float pa  = (px1 - px0) * (py1 - py0);

  int4 lab = labels4[jq];
  const int* labp = &lab.x;
  const float* ccrow = USE_TABLE ? (cc2 + i * CN) : nullptr;
  const float* lgrow = USE_TABLE ? nullptr : (logits + i * CN);

  float res[4];
#pragma unroll
  for (int k = 0; k < 4; ++k) {
    float4 t = target_boxes[jq * 4 + k];
    // L1 in center format
    float l1 = fabsf(p.x - t.x) + fabsf(p.y - t.y) +
               fabsf(p.z - t.z) + fabsf(p.w - t.w);
    // corners
    float tx0 = t.x - 0.5f * t.z, ty0 = t.y - 0.5f * t.w;
    float tx1 = t.x + 0.5f * t.z, ty1 = t.y + 0.5f * t.w;
    float ta  = (tx1 - tx0) * (ty1 - ty0);
    // iou
    float ltx = fmaxf(px0, tx0), lty = fmaxf(py0, ty0);
    float rbx = fminf(px1, tx1), rby = fminf(py1, ty1);
    float iw = fmaxf(rbx - ltx, 0.0f), ih = fmaxf(rby - lty, 0.0f);
    float inter = iw * ih;
    float uni = pa + ta - inter;
    float iou = inter / uni;
    // enclosing box
    float ex0 = fminf(px0, tx0), ey0 = fminf(py0, ty0);
    float ex1 = fmaxf(px1, tx1), ey1 = fmaxf(py1, ty1);
    float ew = fmaxf(ex1 - ex0, 0.0f), eh = fmaxf(ey1 - ey0, 0.0f);
    float enc = ew * eh;
    float giou = iou - (enc - uni) / enc;

    int l = labp[k];
    float cls;
    if (USE_TABLE) {
      cls = ccrow[l];
    } else {
      float x = lgrow[l];
      float pr = 1.0f / (1.0f + expf(-x));
      float neg = 0.75f * pr * pr * (-logf(1.0f - pr + 1e-8f));
      float pos = 0.25f * (1.0f - pr) * (1.0f - pr) * (-logf(pr + 1e-8f));
      cls = 2.0f * (pos - neg);
    }
    res[k] = 5.0f * l1 + cls - 2.0f * giou;
  }
  out[tid] = make_float4(res[0], res[1], res[2], res[3]);
}

extern "C" void kernel_launch(void* const* d_in, const int* in_sizes, int n_in,
                              void* d_out, int out_size, void* d_ws, size_t ws_size,
                              hipStream_t stream) {
  const float*  logits = (const float*)d_in[0];
  const float4* pred   = (const float4*)d_in[1];
  const int4*   labels = (const int4*)d_in[2];
  const float4* tboxes = (const float4*)d_in[3];
  float4* out = (float4*)d_out;

  size_t need = (size_t)NQ * CN * sizeof(float);   // 3.07 MB
  int pair_threads = NQ * JQ;                      // 7,680,000
  int pair_blocks = (pair_threads + 255) / 256;    // 30000

  if (ws_size >= need) {
    float* cc2 = (float*)d_ws;
    int n = NQ * CN;
    class_cost_kernel<<<(n + 255) / 256, 256, 0, stream>>>(logits, cc2, n);
    pair_kernel<true><<<pair_blocks, 256, 0, stream>>>(
        pred, tboxes, labels, cc2, logits, out);
  } else {
    pair_kernel<false><<<pair_blocks, 256, 0, stream>>>(
        pred, tboxes, labels, nullptr, logits, out);
  }
}

// Round 2
// 162.823 us; speedup vs baseline: 1.0548x; 1.0548x over previous
//
#include <hip/hip_runtime.h>

// RT-DETR Hungarian matcher cost matrix.
// B=32, Q=300, C=80, T=100. Out: (B*Q) x (B*T) = 9600 x 3200 fp32 = 122.9 MB.
// cost = 5*L1(center boxes) + 2*focal_class_cost - 2*GIoU
//
// R1 structure: transpose — each thread owns 4 consecutive targets (their
// centers/corners/areas/label-offsets pinned in registers), loops over 32
// query rows per block. Removes per-element target-geometry recompute and
// replaces IEEE divs with v_rcp_f32. class_cost(i, label) precomputed into
// d_ws (removes exp/log from the 30.7M-element pair loop).

constexpr int BB = 32, QQ = 300, CN = 80, TT = 100;
constexpr int NQ = BB * QQ;       // 9600 query rows
constexpr int NT = BB * TT;       // 3200 targets
constexpr int JG = NT / 4;        // 800 groups of 4 targets
constexpr int RCHUNK = 32;        // query rows per block (9600 = 300 * 32)
constexpr int STRIPES = (JG + 255) / 256;   // 4 column stripes

__global__ __launch_bounds__(256) void class_cost_kernel(
    const float* __restrict__ logits, float* __restrict__ cc2, int n) {
  int idx = blockIdx.x * blockDim.x + threadIdx.x;
  if (idx >= n) return;
  float x = logits[idx];
  float p = 1.0f / (1.0f + expf(-x));
  float neg = 0.75f * p * p * (-logf(1.0f - p + 1e-8f));
  float pos = 0.25f * (1.0f - p) * (1.0f - p) * (-logf(p + 1e-8f));
  cc2[idx] = 2.0f * (pos - neg);   // pre-scaled by C_CLASS=2
}

__global__ __launch_bounds__(256, 4) void pair_kernel(
    const float4* __restrict__ pred_boxes,    // NQ   (cx,cy,w,h)
    const float4* __restrict__ target_boxes,  // NT   (cx,cy,w,h)
    const int*    __restrict__ labels,        // NT
    const float*  __restrict__ cc2,           // NQ*80, pre-scaled
    float4*       __restrict__ out)           // NQ * JG
{
  const int tid  = threadIdx.x;
  const int jg   = blockIdx.x * 256 + tid;    // target group [0, 800)
  const int row0 = blockIdx.y * RCHUNK;

  __shared__ float4 s_pred[RCHUNK];
  if (tid < RCHUNK) s_pred[tid] = pred_boxes[row0 + tid];
  __syncthreads();                             // no further barriers below
  if (jg >= JG) return;

  // ---- per-block target state: 4 targets, pinned in registers ----
  float tcx[4], tcy[4], tw[4], th[4];
  float tx0[4], ty0[4], tx1[4], ty1[4], ta[4];
  int   loff[4];
#pragma unroll
  for (int k = 0; k < 4; ++k) {
    float4 t = target_boxes[jg * 4 + k];
    tcx[k] = t.x; tcy[k] = t.y; tw[k] = t.z; th[k] = t.w;
    tx0[k] = t.x - 0.5f * t.z;  ty0[k] = t.y - 0.5f * t.w;
    tx1[k] = t.x + 0.5f * t.z;  ty1[k] = t.y + 0.5f * t.w;
    ta[k]  = (tx1[k] - tx0[k]) * (ty1[k] - ty0[k]);
    loff[k] = labels[jg * 4 + k];
  }

  const size_t outbase = (size_t)jg;
  for (int r = 0; r < RCHUNK; ++r) {
    const int i = row0 + r;
    float4 p = s_pred[r];                      // LDS broadcast, conflict-free
    float px0 = p.x - 0.5f * p.z, py0 = p.y - 0.5f * p.w;
    float px1 = p.x + 0.5f * p.z, py1 = p.y + 0.5f * p.w;
    float pa  = (px1 - px0) * (py1 - py0);
    const float* ccrow = cc2 + (size_t)i * CN;

    float res[4];
#pragma unroll
    for (int k = 0; k < 4; ++k) {
      // L1 in center format
      float l1 = fabsf(p.x - tcx[k]) + fabsf(p.y - tcy[k]) +
                 fabsf(p.z - tw[k])  + fabsf(p.w - th[k]);
      // intersection
      float ltx = fmaxf(px0, tx0[k]), lty = fmaxf(py0, ty0[k]);
      float rbx = fminf(px1, tx1[k]), rby = fminf(py1, ty1[k]);
      float iw = fmaxf(rbx - ltx, 0.0f), ih = fmaxf(rby - lty, 0.0f);
      float inter = iw * ih;
      float uni = pa + ta[k] - inter;
      float iou = inter * __builtin_amdgcn_rcpf(uni);
      // enclosing box (always >= both boxes; fp max-min >= 0, no clamp needed)
      float ex0 = fminf(px0, tx0[k]), ey0 = fminf(py0, ty0[k]);
      float ex1 = fmaxf(px1, tx1[k]), ey1 = fmaxf(py1, ty1[k]);
      float enc = (ex1 - ex0) * (ey1 - ey0);
      float giou = iou - (enc - uni) * __builtin_amdgcn_rcpf(enc);
      // cost = 5*l1 + 2*class + 2*(-giou); cc2 is pre-scaled by 2
      res[k] = 5.0f * l1 + ccrow[loff[k]] - 2.0f * giou;
    }
    out[(size_t)i * JG + outbase] = make_float4(res[0], res[1], res[2], res[3]);
  }
}

__global__ __launch_bounds__(256, 4) void pair_kernel_nows(
    const float4* __restrict__ pred_boxes,
    const float4* __restrict__ target_boxes,
    const int*    __restrict__ labels,
    const float*  __restrict__ logits,        // gather logits, focal inline
    float4*       __restrict__ out)
{
  const int tid  = threadIdx.x;
  const int jg   = blockIdx.x * 256 + tid;
  const int row0 = blockIdx.y * RCHUNK;

  __shared__ float4 s_pred[RCHUNK];
  if (tid < RCHUNK) s_pred[tid] = pred_boxes[row0 + tid];
  __syncthreads();
  if (jg >= JG) return;

  float tcx[4], tcy[4], tw[4], th[4];
  float tx0[4], ty0[4], tx1[4], ty1[4], ta[4];
  int   loff[4];
#pragma unroll
  for (int k = 0; k < 4; ++k) {
    float4 t = target_boxes[jg * 4 + k];
    tcx[k] = t.x; tcy[k] = t.y; tw[k] = t.z; th[k] = t.w;
    tx0[k] = t.x - 0.5f * t.z;  ty0[k] = t.y - 0.5f * t.w;
    tx1[k] = t.x + 0.5f * t.z;  ty1[k] = t.y + 0.5f * t.w;
    ta[k]  = (tx1[k] - tx0[k]) * (ty1[k] - ty0[k]);
    loff[k] = labels[jg * 4 + k];
  }

  for (int r = 0; r < RCHUNK; ++r) {
    const int i = row0 + r;
    float4 p = s_pred[r];
    float px0 = p.x - 0.5f * p.z, py0 = p.y - 0.5f * p.w;
    float px1 = p.x + 0.5f * p.z, py1 = p.y + 0.5f * p.w;
    float pa  = (px1 - px0) * (py1 - py0);
    const float* lgrow = logits + (size_t)i * CN;

    float res[4];
#pragma unroll
    for (int k = 0; k < 4; ++k) {
      float l1 = fabsf(p.x - tcx[k]) + fabsf(p.y - tcy[k]) +
                 fabsf(p.z - tw[k])  + fabsf(p.w - th[k]);
      float ltx = fmaxf(px0, tx0[k]), lty = fmaxf(py0, ty0[k]);
      float rbx = fminf(px1, tx1[k]), rby = fminf(py1, ty1[k]);
      float iw = fmaxf(rbx - ltx, 0.0f), ih = fmaxf(rby - lty, 0.0f);
      float inter = iw * ih;
      float uni = pa + ta[k] - inter;
      float iou = inter * __builtin_amdgcn_rcpf(uni);
      float ex0 = fminf(px0, tx0[k]), ey0 = fminf(py0, ty0[k]);
      float ex1 = fmaxf(px1, tx1[k]), ey1 = fmaxf(py1, ty1[k]);
      float enc = (ex1 - ex0) * (ey1 - ey0);
      float giou = iou - (enc - uni) * __builtin_amdgcn_rcpf(enc);

      float x = lgrow[loff[k]];
      float pr = 1.0f / (1.0f + expf(-x));
      float neg = 0.75f * pr * pr * (-logf(1.0f - pr + 1e-8f));
      float pos = 0.25f * (1.0f - pr) * (1.0f - pr) * (-logf(pr + 1e-8f));
      res[k] = 5.0f * l1 + 2.0f * (pos - neg) - 2.0f * giou;
    }
    out[(size_t)i * JG + jg] = make_float4(res[0], res[1], res[2], res[3]);
  }
}

extern "C" void kernel_launch(void* const* d_in, const int* in_sizes, int n_in,
                              void* d_out, int out_size, void* d_ws, size_t ws_size,
                              hipStream_t stream) {
  const float*  logits = (const float*)d_in[0];
  const float4* pred   = (const float4*)d_in[1];
  const int*    labels = (const int*)d_in[2];
  const float4* tboxes = (const float4*)d_in[3];
  float4* out = (float4*)d_out;

  const size_t need = (size_t)NQ * CN * sizeof(float);   // 3.07 MB
  dim3 grid(STRIPES, NQ / RCHUNK);                       // (4, 300)

  if (ws_size >= need) {
    float* cc2 = (float*)d_ws;
    int n = NQ * CN;
    class_cost_kernel<<<(n + 255) / 256, 256, 0, stream>>>(logits, cc2, n);
    pair_kernel<<<grid, 256, 0, stream>>>(pred, tboxes, labels, cc2, out);
  } else {
    pair_kernel_nows<<<grid, 256, 0, stream>>>(pred, tboxes, labels, logits, out);
  }
}

// Round 3
// 154.258 us; speedup vs baseline: 1.1134x; 1.0555x over previous
//
#include <hip/hip_runtime.h>

// RT-DETR Hungarian matcher cost matrix.
// B=32, Q=300, C=80, T=100. Out: (B*Q) x (B*T) = 9600 x 3200 fp32 = 122.9 MB.
// cost = 5*L1(center boxes) + 2*focal_class_cost - 2*GIoU
//
// R2: single fused kernel. Each block owns a 32-row x 1024-target tile:
//  - fill phase: compute the block's 32x80 focal-class-cost slice from
//    logits into LDS (coalesced, 10 entries/thread, transcendentals off the
//    hot path; 4x stripe redundancy is negligible),
//  - pair phase: each thread pins 4 targets' geometry in registers and loops
//    32 query rows; class gather now hits LDS (~2-way bank alias = free)
//    instead of L1; both divides are v_rcp_f32.
// No d_ws use, one dispatch.

constexpr int BB = 32, QQ = 300, CN = 80, TT = 100;
constexpr int NQ = BB * QQ;       // 9600 query rows
constexpr int NT = BB * TT;       // 3200 targets
constexpr int JG = NT / 4;        // 800 groups of 4 targets
constexpr int RCHUNK = 32;        // query rows per block (9600 = 300 * 32)
constexpr int STRIPES = (JG + 255) / 256;   // 4 column stripes
constexpr int CCN = RCHUNK * CN;  // 2560 class-cost entries per block

__global__ __launch_bounds__(256, 4) void fused_kernel(
    const float*  __restrict__ logits,        // NQ*80
    const float4* __restrict__ pred_boxes,    // NQ   (cx,cy,w,h)
    const int*    __restrict__ labels,        // NT
    const float4* __restrict__ target_boxes,  // NT   (cx,cy,w,h)
    float4*       __restrict__ out)           // NQ * JG
{
  const int tid  = threadIdx.x;
  const int jg   = blockIdx.x * 256 + tid;    // target group [0, 800)
  const int row0 = blockIdx.y * RCHUNK;

  __shared__ float  s_cc[CCN];                // [32 rows][80 classes], 10 KB
  __shared__ float4 s_pred[RCHUNK];

  // ---- fill phase: focal class cost for this block's 32 rows ----
  const float* lgbase = logits + (size_t)row0 * CN;
#pragma unroll
  for (int e = tid; e < CCN; e += 256) {
    float x = lgbase[e];
    float p = 1.0f / (1.0f + expf(-x));
    float neg = 0.75f * p * p * (-logf(1.0f - p + 1e-8f));
    float pos = 0.25f * (1.0f - p) * (1.0f - p) * (-logf(p + 1e-8f));
    s_cc[e] = 2.0f * (pos - neg);             // pre-scaled by C_CLASS=2
  }
  if (tid < RCHUNK) s_pred[tid] = pred_boxes[row0 + tid];
  __syncthreads();
  if (jg >= JG) return;

  // ---- per-thread target state: 4 targets, pinned in registers ----
  float tcx[4], tcy[4], tw[4], th[4];
  float tx0[4], ty0[4], tx1[4], ty1[4], ta[4];
  int   loff[4];
#pragma unroll
  for (int k = 0; k < 4; ++k) {
    float4 t = target_boxes[jg * 4 + k];
    tcx[k] = t.x; tcy[k] = t.y; tw[k] = t.z; th[k] = t.w;
    tx0[k] = t.x - 0.5f * t.z;  ty0[k] = t.y - 0.5f * t.w;
    tx1[k] = t.x + 0.5f * t.z;  ty1[k] = t.y + 0.5f * t.w;
    ta[k]  = (tx1[k] - tx0[k]) * (ty1[k] - ty0[k]);
    loff[k] = labels[jg * 4 + k];
  }

  for (int r = 0; r < RCHUNK; ++r) {
    const int i = row0 + r;
    float4 p = s_pred[r];                      // wave-uniform LDS broadcast
    float px0 = p.x - 0.5f * p.z, py0 = p.y - 0.5f * p.w;
    float px1 = p.x + 0.5f * p.z, py1 = p.y + 0.5f * p.w;
    float pa  = (px1 - px0) * (py1 - py0);
    const float* ccrow = s_cc + r * CN;

    float res[4];
#pragma unroll
    for (int k = 0; k < 4; ++k) {
      // L1 in center format
      float l1 = fabsf(p.x - tcx[k]) + fabsf(p.y - tcy[k]) +
                 fabsf(p.z - tw[k])  + fabsf(p.w - th[k]);
      // intersection
      float ltx = fmaxf(px0, tx0[k]), lty = fmaxf(py0, ty0[k]);
      float rbx = fminf(px1, tx1[k]), rby = fminf(py1, ty1[k]);
      float iw = fmaxf(rbx - ltx, 0.0f), ih = fmaxf(rby - lty, 0.0f);
      float inter = iw * ih;
      float uni = pa + ta[k] - inter;
      float iou = inter * __builtin_amdgcn_rcpf(uni);
      // enclosing box (max-min always >= 0 here, no clamp needed)
      float ex0 = fminf(px0, tx0[k]), ey0 = fminf(py0, ty0[k]);
      float ex1 = fmaxf(px1, tx1[k]), ey1 = fmaxf(py1, ty1[k]);
      float enc = (ex1 - ex0) * (ey1 - ey0);
      float giou = iou - (enc - uni) * __builtin_amdgcn_rcpf(enc);
      // cost = 5*l1 + 2*class + 2*(-giou); s_cc pre-scaled by 2
      res[k] = 5.0f * l1 + ccrow[loff[k]] - 2.0f * giou;
    }
    out[(size_t)i * JG + jg] = make_float4(res[0], res[1], res[2], res[3]);
  }
}

extern "C" void kernel_launch(void* const* d_in, const int* in_sizes, int n_in,
                              void* d_out, int out_size, void* d_ws, size_t ws_size,
                              hipStream_t stream) {
  const float*  logits = (const float*)d_in[0];
  const float4* pred   = (const float4*)d_in[1];
  const int*    labels = (const int*)d_in[2];
  const float4* tboxes = (const float4*)d_in[3];
  float4* out = (float4*)d_out;

  dim3 grid(STRIPES, NQ / RCHUNK);             // (4, 300) = 1200 blocks
  fused_kernel<<<grid, 256, 0, stream>>>(logits, pred, labels, tboxes, out);
}

// Round 4
// 153.304 us; speedup vs baseline: 1.1203x; 1.0062x over previous
//
#include <hip/hip_runtime.h>

// RT-DETR Hungarian matcher cost matrix.
// B=32, Q=300, C=80, T=100. Out: (B*Q) x (B*T) = 9600 x 3200 fp32 = 122.9 MB.
// cost = 5*L1 + 2*focal_class - 2*GIoU
//
// R3: - fully unroll the 32-row loop: LDS gather offsets become immediates
//       (ds_read_b32 base+r*320), scheduler pipelines loads across rows.
//     - giou algebra: -2*giou = 2 - 2*iou - 2*uni/enc; the +2 is pre-folded
//       into the class table (s_cc = 2*(pos-neg) + 2).
//     - launch_bounds(256,3) so the unroll doesn't spill.

constexpr int BB = 32, QQ = 300, CN = 80, TT = 100;
constexpr int NQ = BB * QQ;       // 9600 query rows
constexpr int NT = BB * TT;       // 3200 targets
constexpr int JG = NT / 4;        // 800 groups of 4 targets
constexpr int RCHUNK = 32;        // query rows per block (9600 = 300 * 32)
constexpr int STRIPES = (JG + 255) / 256;   // 4 column stripes
constexpr int CCN = RCHUNK * CN;  // 2560 class-cost entries per block

__global__ __launch_bounds__(256, 3) void fused_kernel(
    const float*  __restrict__ logits,        // NQ*80
    const float4* __restrict__ pred_boxes,    // NQ   (cx,cy,w,h)
    const int*    __restrict__ labels,        // NT
    const float4* __restrict__ target_boxes,  // NT   (cx,cy,w,h)
    float4*       __restrict__ out)           // NQ * JG
{
  const int tid  = threadIdx.x;
  const int jg   = blockIdx.x * 256 + tid;    // target group [0, 800)
  const int row0 = blockIdx.y * RCHUNK;

  __shared__ float  s_cc[CCN];                // [32 rows][80 classes], 10 KB
  __shared__ float4 s_pred[RCHUNK];

  // ---- fill phase: focal class cost (+2 giou-constant bias) ----
  const float* lgbase = logits + (size_t)row0 * CN;
  for (int e = tid; e < CCN; e += 256) {
    float x = lgbase[e];
    float p = 1.0f / (1.0f + expf(-x));
    float neg = 0.75f * p * p * (-logf(1.0f - p + 1e-8f));
    float pos = 0.25f * (1.0f - p) * (1.0f - p) * (-logf(p + 1e-8f));
    s_cc[e] = 2.0f * (pos - neg) + 2.0f;      // C_CLASS=2 pre-scaled, +2 bias
  }
  if (tid < RCHUNK) s_pred[tid] = pred_boxes[row0 + tid];
  __syncthreads();
  if (jg >= JG) return;

  // ---- per-thread target state: 4 targets, pinned in registers ----
  float tcx[4], tcy[4], tw[4], th[4];
  float tx0[4], ty0[4], tx1[4], ty1[4], ta[4];
  const float* ccbase[4];                     // s_cc + label; row via imm offset
#pragma unroll
  for (int k = 0; k < 4; ++k) {
    float4 t = target_boxes[jg * 4 + k];
    tcx[k] = t.x; tcy[k] = t.y; tw[k] = t.z; th[k] = t.w;
    tx0[k] = t.x - 0.5f * t.z;  ty0[k] = t.y - 0.5f * t.w;
    tx1[k] = t.x + 0.5f * t.z;  ty1[k] = t.y + 0.5f * t.w;
    ta[k]  = (tx1[k] - tx0[k]) * (ty1[k] - ty0[k]);
    ccbase[k] = s_cc + labels[jg * 4 + k];
  }

  float4* outp = out + (size_t)row0 * JG + jg;

#pragma unroll
  for (int r = 0; r < RCHUNK; ++r) {
    float4 p = s_pred[r];                      // imm-offset ds_read_b128
    float px0 = p.x - 0.5f * p.z, py0 = p.y - 0.5f * p.w;
    float px1 = p.x + 0.5f * p.z, py1 = p.y + 0.5f * p.w;
    float pa  = (px1 - px0) * (py1 - py0);

    float res[4];
#pragma unroll
    for (int k = 0; k < 4; ++k) {
      // L1 in center format
      float l1 = fabsf(p.x - tcx[k]) + fabsf(p.y - tcy[k]) +
                 fabsf(p.z - tw[k])  + fabsf(p.w - th[k]);
      // intersection
      float ltx = fmaxf(px0, tx0[k]), lty = fmaxf(py0, ty0[k]);
      float rbx = fminf(px1, tx1[k]), rby = fminf(py1, ty1[k]);
      float iw = fmaxf(rbx - ltx, 0.0f), ih = fmaxf(rby - lty, 0.0f);
      float inter = iw * ih;
      float uni = pa + ta[k] - inter;
      // enclosing box (max-min >= 0 here, no clamp needed)
      float ex0 = fminf(px0, tx0[k]), ey0 = fminf(py0, ty0[k]);
      float ex1 = fmaxf(px1, tx1[k]), ey1 = fmaxf(py1, ty1[k]);
      float enc = (ex1 - ex0) * (ey1 - ey0);
      // -2*giou = 2 - 2*iou - 2*uni/enc; +2 lives in the class table
      float iou   = inter * __builtin_amdgcn_rcpf(uni);
      float une   = uni   * __builtin_amdgcn_rcpf(enc);
      float cls   = ccbase[k][r * CN];         // ds_read_b32, imm offset r*320
      float acc   = fmaf(5.0f, l1, cls);
      acc         = fmaf(-2.0f, iou, acc);
      res[k]      = fmaf(-2.0f, une, acc);
    }
    outp[(size_t)r * JG] = make_float4(res[0], res[1], res[2], res[3]);
  }
}

extern "C" void kernel_launch(void* const* d_in, const int* in_sizes, int n_in,
                              void* d_out, int out_size, void* d_ws, size_t ws_size,
                              hipStream_t stream) {
  const float*  logits = (const float*)d_in[0];
  const float4* pred   = (const float4*)d_in[1];
  const int*    labels = (const int*)d_in[2];
  const float4* tboxes = (const float4*)d_in[3];
  float4* out = (float4*)d_out;

  dim3 grid(STRIPES, NQ / RCHUNK);             // (4, 300) = 1200 blocks
  fused_kernel<<<grid, 256, 0, stream>>>(logits, pred, labels, tboxes, out);
}